// Round 1
// baseline (197.055 us; speedup 1.0000x reference)
//
#include <hip/hip_runtime.h>
#include <math.h>

#define B_SZ 32
#define L_SZ 32768
#define T_SZ 1024
#define PS_SZ 32
#define D_SZ 256
#define SM_M 10.0f   // static softmax max-shift; scores ~N(0,1), max << 10

typedef float f32x4 __attribute__((ext_vector_type(4)));
typedef float f32x16 __attribute__((ext_vector_type(16)));
typedef short s16x8 __attribute__((ext_vector_type(8)));
typedef unsigned short u16x8 __attribute__((ext_vector_type(8)));

__device__ __forceinline__ unsigned short f2bf(float f) {
  union { float f; unsigned int u; } v; v.f = f;
  unsigned int r = v.u + 0x7FFFu + ((v.u >> 16) & 1u);
  return (unsigned short)(r >> 16);
}

__device__ __forceinline__ void g2l16(const unsigned short* g, unsigned short* l) {
  __builtin_amdgcn_global_load_lds(
      (const __attribute__((address_space(1))) unsigned int*)g,
      (__attribute__((address_space(3))) unsigned int*)l, 16, 0, 0);
}

// ---------------- prep: stats partials + weight folds + counter zero ----------------
__global__ __launch_bounds__(256) void prep_kernel(const float* __restrict__ x,
                                                   float* __restrict__ sgpart,
                                                   const float* __restrict__ Wp,
                                                   const float* __restrict__ bp,
                                                   const float* __restrict__ Wq,
                                                   const float* __restrict__ bq,
                                                   const float* __restrict__ Wo,
                                                   const float* __restrict__ bo,
                                                   const float* __restrict__ Wh,
                                                   const float* __restrict__ bh,
                                                   float* __restrict__ Wcb,
                                                   unsigned short* __restrict__ WqT,
                                                   unsigned short* __restrict__ WfT,
                                                   float* __restrict__ bfp,
                                                   unsigned int* __restrict__ total,
                                                   float* __restrict__ lsum) {
  __shared__ float red[8];
  const int g = blockIdx.x, tid = threadIdx.x;
  const int w = tid >> 6, lane = tid & 63;
  if (g < 256) {
    const int b = g >> 3;
    const float* p = x + (size_t)b * L_SZ + (size_t)(g & 7) * 4096;
    float s = 0.f, ss = 0.f;
#pragma unroll
    for (int i = 0; i < 4; ++i) {
      float4 f = ((const float4*)p)[tid + i * 256];
      s += f.x + f.y + f.z + f.w;
      ss += f.x * f.x + f.y * f.y + f.z * f.z + f.w * f.w;
    }
#pragma unroll
    for (int off = 32; off >= 1; off >>= 1) {
      s += __shfl_down(s, off);
      ss += __shfl_down(ss, off);
    }
    if (lane == 0) { red[w] = s; red[4 + w] = ss; }
    __syncthreads();
    if (tid == 0) {
      sgpart[g * 2]     = red[0] + red[1] + red[2] + red[3];
      sgpart[g * 2 + 1] = red[4] + red[5] + red[6] + red[7];
    }
  } else if (g < 388) {
    int idx = (g - 256) * 256 + tid;
    if (idx < 33 * 768) {
      int p = idx / 768, j = idx % 768;
      const float* arow = (p < 32) ? (Wp + p * 256) : bp;
      float acc = (p < 32) ? 0.f : bq[j];
      for (int d = 0; d < 256; ++d) acc += arow[d] * Wq[d * 768 + j];
      if (p < 32) WqT[j * 32 + p] = f2bf(acc);
      else Wcb[j] = acc;
    } else {
      int k = idx - 33 * 768;
      if (k < 8192) {
        int p = k >> 8, d = k & 255;
        float acc = 0.f;
        for (int e = 0; e < 256; ++e) acc += Wo[d * 256 + e] * Wh[e * 32 + p];
        WfT[p * 256 + d] = f2bf(acc);
      } else if (k < 8224) {
        int p = k - 8192;
        float acc = bh[p];
        for (int e = 0; e < 256; ++e) acc += bo[e] * Wh[e * 32 + p];
        bfp[p] = acc;
      }
    }
  } else {
    if (tid == 0) { total[0] = 0u; lsum[0] = 0.f; }
  }
}

// ---------------- qkv MFMA GEMM (verified R7/R9); V kt-tiled transposed ----------------
__global__ __launch_bounds__(256) void qkv_kernel(const float* __restrict__ x,
                                                  const float* __restrict__ sgpart,
                                                  const unsigned short* __restrict__ WqT,
                                                  const float* __restrict__ Wcb,
                                                  unsigned short* __restrict__ Qb,
                                                  unsigned short* __restrict__ Kb,
                                                  unsigned short* __restrict__ Vtt) {
  __shared__ unsigned short T4[4][8448];
  const int tid = threadIdx.x;
  const int w = tid >> 6, lane = tid & 63;
  const int lo = lane & 15, quad = lane >> 4;
  unsigned short* Tw = T4[w];
  const int mbase = blockIdx.x * 128 + w * 32;
  const int b = mbase >> 10;
  float S = 0.f, SS = 0.f;
#pragma unroll
  for (int i = 0; i < 8; ++i) {
    S += sgpart[(b * 8 + i) * 2];
    SS += sgpart[(b * 8 + i) * 2 + 1];
  }
  const float mean = S * (1.f / (float)L_SZ);
  const float var = (SS - S * mean) * (1.f / (float)(L_SZ - 1));
  const float inv = 1.f / (sqrtf(var) + 1e-5f);
  s16x8 af0, af1;
  {
    float4 a = *(const float4*)&x[(size_t)(mbase + lo) * 32 + quad * 8];
    float4 c = *(const float4*)&x[(size_t)(mbase + lo) * 32 + quad * 8 + 4];
    af0[0] = (short)f2bf((a.x - mean) * inv); af0[1] = (short)f2bf((a.y - mean) * inv);
    af0[2] = (short)f2bf((a.z - mean) * inv); af0[3] = (short)f2bf((a.w - mean) * inv);
    af0[4] = (short)f2bf((c.x - mean) * inv); af0[5] = (short)f2bf((c.y - mean) * inv);
    af0[6] = (short)f2bf((c.z - mean) * inv); af0[7] = (short)f2bf((c.w - mean) * inv);
    float4 d = *(const float4*)&x[(size_t)(mbase + 16 + lo) * 32 + quad * 8];
    float4 e = *(const float4*)&x[(size_t)(mbase + 16 + lo) * 32 + quad * 8 + 4];
    af1[0] = (short)f2bf((d.x - mean) * inv); af1[1] = (short)f2bf((d.y - mean) * inv);
    af1[2] = (short)f2bf((d.z - mean) * inv); af1[3] = (short)f2bf((d.w - mean) * inv);
    af1[4] = (short)f2bf((e.x - mean) * inv); af1[5] = (short)f2bf((e.y - mean) * inv);
    af1[6] = (short)f2bf((e.z - mean) * inv); af1[7] = (short)f2bf((e.w - mean) * inv);
  }
  // Q (pre-scaled 1/16)
#pragma unroll 4
  for (int nt = 0; nt < 16; ++nt) {
    s16x8 bf = *(const s16x8*)&WqT[(size_t)(nt * 16 + lo) * 32 + quad * 8];
    f32x4 c0 = {0.f, 0.f, 0.f, 0.f}, c1 = {0.f, 0.f, 0.f, 0.f};
    c0 = __builtin_amdgcn_mfma_f32_16x16x32_bf16(af0, bf, c0, 0, 0, 0);
    c1 = __builtin_amdgcn_mfma_f32_16x16x32_bf16(af1, bf, c1, 0, 0, 0);
    const int col = nt * 16 + lo;
    const float bi = Wcb[col];
#pragma unroll
    for (int i = 0; i < 4; ++i) {
      Tw[(quad * 4 + i) * 264 + col]      = f2bf((c0[i] + bi) * 0.0625f);
      Tw[(16 + quad * 4 + i) * 264 + col] = f2bf((c1[i] + bi) * 0.0625f);
    }
  }
#pragma unroll
  for (int it = 0; it < 16; ++it) {
    const int gsub = it * 64 + lane;
    const int row = gsub >> 5, c16 = gsub & 31;
    *(u16x8*)&Qb[(size_t)(mbase + row) * 256 + c16 * 8] =
        *(const u16x8*)&Tw[row * 264 + c16 * 8];
  }
  // K
#pragma unroll 4
  for (int nt = 0; nt < 16; ++nt) {
    s16x8 bf = *(const s16x8*)&WqT[(size_t)(256 + nt * 16 + lo) * 32 + quad * 8];
    f32x4 c0 = {0.f, 0.f, 0.f, 0.f}, c1 = {0.f, 0.f, 0.f, 0.f};
    c0 = __builtin_amdgcn_mfma_f32_16x16x32_bf16(af0, bf, c0, 0, 0, 0);
    c1 = __builtin_amdgcn_mfma_f32_16x16x32_bf16(af1, bf, c1, 0, 0, 0);
    const int col = nt * 16 + lo;
    const float bi = Wcb[256 + col];
#pragma unroll
    for (int i = 0; i < 4; ++i) {
      Tw[(quad * 4 + i) * 264 + col]      = f2bf(c0[i] + bi);
      Tw[(16 + quad * 4 + i) * 264 + col] = f2bf(c1[i] + bi);
    }
  }
#pragma unroll
  for (int it = 0; it < 16; ++it) {
    const int gsub = it * 64 + lane;
    const int row = gsub >> 5, c16 = gsub & 31;
    *(u16x8*)&Kb[(size_t)(mbase + row) * 256 + c16 * 8] =
        *(const u16x8*)&Tw[row * 264 + c16 * 8];
  }
  // V transposed, kt-tiled: Vtt[(b*32+ktq)*8192 + d*32 + t_local]
#pragma unroll 4
  for (int nt2 = 0; nt2 < 16; ++nt2) {
    s16x8 aw = *(const s16x8*)&WqT[(size_t)(512 + nt2 * 16 + lo) * 32 + quad * 8];
    f32x4 c0 = {0.f, 0.f, 0.f, 0.f}, c1 = {0.f, 0.f, 0.f, 0.f};
    c0 = __builtin_amdgcn_mfma_f32_16x16x32_bf16(aw, af0, c0, 0, 0, 0);
    c1 = __builtin_amdgcn_mfma_f32_16x16x32_bf16(aw, af1, c1, 0, 0, 0);
#pragma unroll
    for (int i = 0; i < 4; ++i) {
      const int d = nt2 * 16 + quad * 4 + i;
      const float bv = Wcb[512 + d];
      Tw[d * 32 + lo]      = f2bf(c0[i] + bv);
      Tw[d * 32 + 16 + lo] = f2bf(c1[i] + bv);
    }
  }
  {
    const int ktq = (mbase >> 5) & 31;
    const size_t vb = ((size_t)b * 32 + ktq) * 8192;
#pragma unroll
    for (int it = 0; it < 16; ++it) {
      const int gsub = it * 64 + lane;
      *(u16x8*)&Vtt[vb + gsub * 8] = *(const u16x8*)&Tw[gsub * 8];
    }
  }
}

// ---------------- flash attention: 32 q-rows/wave via 32x32x16 MFMA ----------------
// 512 blocks x 128 threads (2 waves). Each wave owns 32 q rows => each K/V LDS byte
// feeds 2x the q-work of the old 16-row version (LDS read volume halved).
// Balanced pairing: first 256 blocks qt=15..8, second 256 qt=0..7, so the 2 resident
// blocks per CU always sum to 34 kt-steps. XCD pinned by b (g%8).
// LDS (shorts): buf0 K[0,8192) V[8192,16384) | buf1 [16384,32768) | P 2x[32x56]
// K swizzle: 16B-chunk ^ (key&31) (conflict-free); V^T: chunk ^ ((d>>2)&3).
__global__ __launch_bounds__(128, 1) void attn_kernel(const unsigned short* __restrict__ Qb,
                                                      const unsigned short* __restrict__ Kb,
                                                      const unsigned short* __restrict__ Vtt,
                                                      const unsigned short* __restrict__ WfT,
                                                      const float* __restrict__ bfp,
                                                      const float* __restrict__ x,
                                                      const float* __restrict__ sgpart,
                                                      float* __restrict__ lsum,
                                                      unsigned int* __restrict__ total,
                                                      float* __restrict__ out) {
  __shared__ unsigned short SMEM[36352];  // 72704 B -> 2 blocks/CU
  __shared__ float redf[2];
  __shared__ unsigned int flag;
  const int g = blockIdx.x;
  const int j = g >> 3;
  const int b = (g & 7) * 4 + (j & 3);                       // XCD id (g%8) pinned per b
  const int qt = (j < 32) ? (15 - (j >> 2)) : ((j - 32) >> 2);  // heavy-first, CU-pair sums 34
  const int tid = threadIdx.x;
  const int w = tid >> 6, lane = tid & 63;
  const int cl = lane & 31, hi = lane >> 5;
  const int qr0 = qt * 64 + w * 32;

  // Q fragments: A of 32x32x16 -> lane holds Q[qr0+cl][16*cb + 8*hi + j]
  s16x8 qf[16];
  {
    const size_t qrow = ((size_t)(b * 1024 + qr0 + cl)) * 256;
#pragma unroll
    for (int cb = 0; cb < 16; ++cb)
      qf[cb] = *(const s16x8*)&Qb[qrow + cb * 16 + hi * 8];
  }

  f32x16 O[8], Ol;
#pragma unroll
  for (int dt = 0; dt < 8; ++dt)
#pragma unroll
    for (int i = 0; i < 16; ++i) O[dt][i] = 0.f;
#pragma unroll
  for (int i = 0; i < 16; ++i) Ol[i] = 0.f;
  s16x8 ones;
#pragma unroll
  for (int jj = 0; jj < 8; ++jj) ones[jj] = (short)0x3F80;

  // staging source offsets (per-thread, kt-invariant); LDS dest is linear,
  // source is inverse-swizzled (both-sides-or-neither rule)
  int kof[8];
#pragma unroll
  for (int it = 0; it < 8; ++it) {
    const int key = it * 4 + (tid >> 5);
    kof[it] = key * 256 + ((tid & 31) ^ key) * 8;
  }
  const int vof = (tid >> 2) * 32 + (((tid & 3) ^ ((tid >> 4) & 3))) * 8;
  const unsigned short* KbB = Kb + (size_t)b * 262144;
  const unsigned short* VtB = Vtt + (size_t)b * 262144;
  const int wb = w * 512;
  const int nk = 2 * (qt + 1);

  // prologue: stage tile 0 into buf 0
#pragma unroll
  for (int it = 0; it < 8; ++it) g2l16(KbB + kof[it], &SMEM[it * 1024 + wb]);
#pragma unroll
  for (int it = 0; it < 8; ++it) g2l16(VtB + vof + it * 1024, &SMEM[8192 + it * 1024 + wb]);

  const int maskl = (cl >> 2) & 3;
  const int cv0 = (hi ^ maskl) * 8;          // V chunk offsets for kb=0/1
  const int cv1 = ((2 | hi) ^ maskl) * 8;
  unsigned short* Pw = &SMEM[32768 + w * 1792];  // 32 x 56 shorts (112B rows, 16B-aligned)
  const int prow = cl * 56;

  for (int kt = 0; kt < nk; ++kt) {
    const int k0 = kt * 32;
    __syncthreads();  // drains vmcnt -> buf[kt&1] fully staged & visible
    const int cur = (kt & 1) << 14;
    if (kt + 1 < nk) {  // prefetch next tile into other buffer; lands during compute
      const int nxt = ((kt + 1) & 1) << 14;
      const int ko = (kt + 1) * 8192;
#pragma unroll
      for (int it = 0; it < 8; ++it) g2l16(KbB + ko + kof[it], &SMEM[nxt + it * 1024 + wb]);
#pragma unroll
      for (int it = 0; it < 8; ++it)
        g2l16(VtB + ko + vof + it * 1024, &SMEM[nxt + 8192 + it * 1024 + wb]);
    }

    if (k0 <= qr0 + 31) {
      // QK^T: S[32q x 32k], contraction 256 in 16 MFMAs
      f32x16 S;
#pragma unroll
      for (int i = 0; i < 16; ++i) S[i] = 0.f;
      const int kbl = cur + cl * 256;
#pragma unroll
      for (int cb = 0; cb < 16; ++cb) {
        s16x8 kf = *(const s16x8*)&SMEM[kbl + ((((cb << 1) | hi) ^ cl) << 3)];
        S = __builtin_amdgcn_mfma_f32_32x32x16_bf16(qf[cb], kf, S, 0, 0, 0);
      }
      const bool diag = (k0 + 31 > qr0);  // straddling tile: causal mask
#pragma unroll
      for (int r = 0; r < 16; ++r) {
        const int row = (r & 3) + 8 * (r >> 2) + 4 * hi;
        float e = __expf(S[r] - SM_M);
        if (diag && (k0 + cl > qr0 + row)) e = 0.f;
        Pw[row * 56 + cl] = f2bf(e);
      }
      s16x8 pf0 = *(const s16x8*)&Pw[prow + hi * 8];
      s16x8 pf1 = *(const s16x8*)&Pw[prow + 16 + hi * 8];
      Ol = __builtin_amdgcn_mfma_f32_32x32x16_bf16(pf0, ones, Ol, 0, 0, 0);
      Ol = __builtin_amdgcn_mfma_f32_32x32x16_bf16(pf1, ones, Ol, 0, 0, 0);
      const int vbl = cur + 8192 + cl * 32;
#pragma unroll
      for (int dt = 0; dt < 8; ++dt) {
        s16x8 v0 = *(const s16x8*)&SMEM[vbl + dt * 1024 + cv0];
        s16x8 v1 = *(const s16x8*)&SMEM[vbl + dt * 1024 + cv1];
        O[dt] = __builtin_amdgcn_mfma_f32_32x32x16_bf16(pf0, v0, O[dt], 0, 0, 0);
        O[dt] = __builtin_amdgcn_mfma_f32_32x32x16_bf16(pf1, v1, O[dt], 0, 0, 0);
      }
    }
  }
  __syncthreads();  // all waves done with buffers before OL overlay

  // ---- epilogue: normalize O -> LDS A-layout -> head GEMM -> fused MSE ----
  unsigned short* OLw = &SMEM[w * 8448];
#pragma unroll
  for (int r = 0; r < 16; ++r) {
    const int row = (r & 3) + 8 * (r >> 2) + 4 * hi;
    const float iv = 1.f / Ol[r];
#pragma unroll
    for (int dt = 0; dt < 8; ++dt)
      OLw[row * 264 + dt * 32 + cl] = f2bf(O[dt][r] * iv);
  }
  s16x8 af[16];
#pragma unroll
  for (int cb = 0; cb < 16; ++cb)
    af[cb] = *(const s16x8*)&OLw[cl * 264 + cb * 16 + hi * 8];

  float S_ = 0.f, SS = 0.f;
#pragma unroll
  for (int i = 0; i < 8; ++i) {
    S_ += sgpart[(b * 8 + i) * 2];
    SS += sgpart[(b * 8 + i) * 2 + 1];
  }
  const float mean = S_ * (1.f / (float)L_SZ);
  const float var = (SS - S_ * mean) * (1.f / (float)(L_SZ - 1));
  const float invb = 1.f / (sqrtf(var) + 1e-5f);

  f32x16 hacc;
#pragma unroll
  for (int i = 0; i < 16; ++i) hacc[i] = 0.f;
#pragma unroll
  for (int cb = 0; cb < 16; ++cb) {
    s16x8 bfr = *(const s16x8*)&WfT[(size_t)cl * 256 + cb * 16 + hi * 8];
    hacc = __builtin_amdgcn_mfma_f32_32x32x16_bf16(af[cb], bfr, hacc, 0, 0, 0);
  }
  const float ba = bfp[cl];
  float lacc = 0.f;
#pragma unroll
  for (int r = 0; r < 16; ++r) {
    const int row = (r & 3) + 8 * (r >> 2) + 4 * hi;
    const int t = qr0 + row;
    if (t < 1023) {
      const float pr = hacc[r] + ba;
      const float tg = (x[(size_t)b * L_SZ + (t + 1) * 32 + cl] - mean) * invb;
      const float d = pr - tg;
      lacc += d * d;
    }
  }
#pragma unroll
  for (int off = 32; off >= 1; off >>= 1) lacc += __shfl_down(lacc, off);
  if (lane == 0) redf[w] = lacc;
  __syncthreads();

  // ---- in-kernel loss finalize (counter pattern verified numerically in R10) ----
  if (tid == 0) {
    atomicAdd(lsum, redf[0] + redf[1]);
    __threadfence();
    unsigned int prev = atomicAdd(total, 1u);
    flag = (prev == 511u) ? 1u : 0u;
  }
  __syncthreads();
  if (flag && tid == 0) {
    float tot = atomicAdd(lsum, 0.0f);  // device-scope read including all adds
    out[0] = tot * (1.f / (float)(B_SZ * (T_SZ - 1) * PS_SZ));
  }
}

extern "C" void kernel_launch(void* const* d_in, const int* in_sizes, int n_in,
                              void* d_out, int out_size, void* d_ws, size_t ws_size,
                              hipStream_t stream) {
  const float* x      = (const float*)d_in[0];
  const float* W_proj = (const float*)d_in[1];
  const float* b_proj = (const float*)d_in[2];
  const float* W_qkv  = (const float*)d_in[3];
  const float* b_qkv  = (const float*)d_in[4];
  const float* W_out  = (const float*)d_in[5];
  const float* b_out  = (const float*)d_in[6];
  const float* W_head = (const float*)d_in[7];
  const float* b_head = (const float*)d_in[8];
  float* out = (float*)d_out;
  char* ws = (char*)d_ws;

  unsigned short* Qb     = (unsigned short*)ws;
  unsigned short* Kb     = (unsigned short*)(ws + (16ull << 20));
  unsigned short* Vtt    = (unsigned short*)(ws + (32ull << 20));
  char* tail = ws + (48ull << 20);
  float*          Wcb    = (float*)tail;                        // 768 fp32 folded qkv bias
  unsigned short* WqT    = (unsigned short*)(tail + 4096);      // 768x32 bf16
  unsigned short* WfT    = (unsigned short*)(tail + 65536);     // 32x256 bf16
  float*          bfp    = (float*)(tail + 98304);              // 32 fp32
  float*          sgpart = (float*)(tail + 102400);             // 256x2 fp32
  unsigned int*   total  = (unsigned int*)(tail + 106496);      // 1 ctr
  float*          lsum   = (float*)(tail + 106496 + 64);        // 1 fp32

  prep_kernel<<<389, 256, 0, stream>>>(x, sgpart, W_proj, b_proj, W_qkv, b_qkv,
                                       W_out, b_out, W_head, b_head,
                                       Wcb, WqT, WfT, bfp, total, lsum);
  qkv_kernel<<<256, 256, 0, stream>>>(x, sgpart, WqT, Wcb, Qb, Kb, Vtt);
  attn_kernel<<<512, 128, 0, stream>>>(Qb, Kb, Vtt, WfT, bfp, x, sgpart, lsum, total, out);
}

// Round 2
// 196.946 us; speedup vs baseline: 1.0005x; 1.0005x over previous
//
#include <hip/hip_runtime.h>
#include <math.h>

#define B_SZ 32
#define L_SZ 32768
#define T_SZ 1024
#define PS_SZ 32
#define D_SZ 256
#define SM_M 10.0f   // static softmax max-shift; scores ~N(0,1), max << 10

typedef float f32x4 __attribute__((ext_vector_type(4)));
typedef float f32x16 __attribute__((ext_vector_type(16)));
typedef short s16x8 __attribute__((ext_vector_type(8)));
typedef unsigned short u16x8 __attribute__((ext_vector_type(8)));
typedef unsigned int u32;
typedef unsigned int u32x4 __attribute__((ext_vector_type(4)));

__device__ __forceinline__ unsigned short f2bf(float f) {
  union { float f; unsigned int u; } v; v.f = f;
  unsigned int r = v.u + 0x7FFFu + ((v.u >> 16) & 1u);
  return (unsigned short)(r >> 16);
}

// ---------------- prep: stats partials + weight folds + counter zero ----------------
__global__ __launch_bounds__(256) void prep_kernel(const float* __restrict__ x,
                                                   float* __restrict__ sgpart,
                                                   const float* __restrict__ Wp,
                                                   const float* __restrict__ bp,
                                                   const float* __restrict__ Wq,
                                                   const float* __restrict__ bq,
                                                   const float* __restrict__ Wo,
                                                   const float* __restrict__ bo,
                                                   const float* __restrict__ Wh,
                                                   const float* __restrict__ bh,
                                                   float* __restrict__ Wcb,
                                                   unsigned short* __restrict__ WqT,
                                                   unsigned short* __restrict__ WfT,
                                                   float* __restrict__ bfp,
                                                   unsigned int* __restrict__ total,
                                                   float* __restrict__ lsum) {
  __shared__ float red[8];
  const int g = blockIdx.x, tid = threadIdx.x;
  const int w = tid >> 6, lane = tid & 63;
  if (g < 256) {
    const int b = g >> 3;
    const float* p = x + (size_t)b * L_SZ + (size_t)(g & 7) * 4096;
    float s = 0.f, ss = 0.f;
#pragma unroll
    for (int i = 0; i < 4; ++i) {
      float4 f = ((const float4*)p)[tid + i * 256];
      s += f.x + f.y + f.z + f.w;
      ss += f.x * f.x + f.y * f.y + f.z * f.z + f.w * f.w;
    }
#pragma unroll
    for (int off = 32; off >= 1; off >>= 1) {
      s += __shfl_down(s, off);
      ss += __shfl_down(ss, off);
    }
    if (lane == 0) { red[w] = s; red[4 + w] = ss; }
    __syncthreads();
    if (tid == 0) {
      sgpart[g * 2]     = red[0] + red[1] + red[2] + red[3];
      sgpart[g * 2 + 1] = red[4] + red[5] + red[6] + red[7];
    }
  } else if (g < 388) {
    int idx = (g - 256) * 256 + tid;
    if (idx < 33 * 768) {
      int p = idx / 768, j = idx % 768;
      const float* arow = (p < 32) ? (Wp + p * 256) : bp;
      float acc = (p < 32) ? 0.f : bq[j];
      for (int d = 0; d < 256; ++d) acc += arow[d] * Wq[d * 768 + j];
      if (p < 32) WqT[j * 32 + p] = f2bf(acc);
      else Wcb[j] = acc;
    } else {
      int k = idx - 33 * 768;
      if (k < 8192) {
        int p = k >> 8, d = k & 255;
        float acc = 0.f;
        for (int e = 0; e < 256; ++e) acc += Wo[d * 256 + e] * Wh[e * 32 + p];
        WfT[p * 256 + d] = f2bf(acc);
      } else if (k < 8224) {
        int p = k - 8192;
        float acc = bh[p];
        for (int e = 0; e < 256; ++e) acc += bo[e] * Wh[e * 32 + p];
        bfp[p] = acc;
      }
    }
  } else {
    if (tid == 0) { total[0] = 0u; lsum[0] = 0.f; }
  }
}

// ---------------- qkv MFMA GEMM (verified R7/R9); V kt-tiled transposed ----------------
__global__ __launch_bounds__(256) void qkv_kernel(const float* __restrict__ x,
                                                  const float* __restrict__ sgpart,
                                                  const unsigned short* __restrict__ WqT,
                                                  const float* __restrict__ Wcb,
                                                  unsigned short* __restrict__ Qb,
                                                  unsigned short* __restrict__ Kb,
                                                  unsigned short* __restrict__ Vtt) {
  __shared__ unsigned short T4[4][8448];
  const int tid = threadIdx.x;
  const int w = tid >> 6, lane = tid & 63;
  const int lo = lane & 15, quad = lane >> 4;
  unsigned short* Tw = T4[w];
  const int mbase = blockIdx.x * 128 + w * 32;
  const int b = mbase >> 10;
  float S = 0.f, SS = 0.f;
#pragma unroll
  for (int i = 0; i < 8; ++i) {
    S += sgpart[(b * 8 + i) * 2];
    SS += sgpart[(b * 8 + i) * 2 + 1];
  }
  const float mean = S * (1.f / (float)L_SZ);
  const float var = (SS - S * mean) * (1.f / (float)(L_SZ - 1));
  const float inv = 1.f / (sqrtf(var) + 1e-5f);
  s16x8 af0, af1;
  {
    float4 a = *(const float4*)&x[(size_t)(mbase + lo) * 32 + quad * 8];
    float4 c = *(const float4*)&x[(size_t)(mbase + lo) * 32 + quad * 8 + 4];
    af0[0] = (short)f2bf((a.x - mean) * inv); af0[1] = (short)f2bf((a.y - mean) * inv);
    af0[2] = (short)f2bf((a.z - mean) * inv); af0[3] = (short)f2bf((a.w - mean) * inv);
    af0[4] = (short)f2bf((c.x - mean) * inv); af0[5] = (short)f2bf((c.y - mean) * inv);
    af0[6] = (short)f2bf((c.z - mean) * inv); af0[7] = (short)f2bf((c.w - mean) * inv);
    float4 d = *(const float4*)&x[(size_t)(mbase + 16 + lo) * 32 + quad * 8];
    float4 e = *(const float4*)&x[(size_t)(mbase + 16 + lo) * 32 + quad * 8 + 4];
    af1[0] = (short)f2bf((d.x - mean) * inv); af1[1] = (short)f2bf((d.y - mean) * inv);
    af1[2] = (short)f2bf((d.z - mean) * inv); af1[3] = (short)f2bf((d.w - mean) * inv);
    af1[4] = (short)f2bf((e.x - mean) * inv); af1[5] = (short)f2bf((e.y - mean) * inv);
    af1[6] = (short)f2bf((e.z - mean) * inv); af1[7] = (short)f2bf((e.w - mean) * inv);
  }
  // Q (pre-scaled 1/16)
#pragma unroll 4
  for (int nt = 0; nt < 16; ++nt) {
    s16x8 bf = *(const s16x8*)&WqT[(size_t)(nt * 16 + lo) * 32 + quad * 8];
    f32x4 c0 = {0.f, 0.f, 0.f, 0.f}, c1 = {0.f, 0.f, 0.f, 0.f};
    c0 = __builtin_amdgcn_mfma_f32_16x16x32_bf16(af0, bf, c0, 0, 0, 0);
    c1 = __builtin_amdgcn_mfma_f32_16x16x32_bf16(af1, bf, c1, 0, 0, 0);
    const int col = nt * 16 + lo;
    const float bi = Wcb[col];
#pragma unroll
    for (int i = 0; i < 4; ++i) {
      Tw[(quad * 4 + i) * 264 + col]      = f2bf((c0[i] + bi) * 0.0625f);
      Tw[(16 + quad * 4 + i) * 264 + col] = f2bf((c1[i] + bi) * 0.0625f);
    }
  }
#pragma unroll
  for (int it = 0; it < 16; ++it) {
    const int gsub = it * 64 + lane;
    const int row = gsub >> 5, c16 = gsub & 31;
    *(u16x8*)&Qb[(size_t)(mbase + row) * 256 + c16 * 8] =
        *(const u16x8*)&Tw[row * 264 + c16 * 8];
  }
  // K
#pragma unroll 4
  for (int nt = 0; nt < 16; ++nt) {
    s16x8 bf = *(const s16x8*)&WqT[(size_t)(256 + nt * 16 + lo) * 32 + quad * 8];
    f32x4 c0 = {0.f, 0.f, 0.f, 0.f}, c1 = {0.f, 0.f, 0.f, 0.f};
    c0 = __builtin_amdgcn_mfma_f32_16x16x32_bf16(af0, bf, c0, 0, 0, 0);
    c1 = __builtin_amdgcn_mfma_f32_16x16x32_bf16(af1, bf, c1, 0, 0, 0);
    const int col = nt * 16 + lo;
    const float bi = Wcb[256 + col];
#pragma unroll
    for (int i = 0; i < 4; ++i) {
      Tw[(quad * 4 + i) * 264 + col]      = f2bf(c0[i] + bi);
      Tw[(16 + quad * 4 + i) * 264 + col] = f2bf(c1[i] + bi);
    }
  }
#pragma unroll
  for (int it = 0; it < 16; ++it) {
    const int gsub = it * 64 + lane;
    const int row = gsub >> 5, c16 = gsub & 31;
    *(u16x8*)&Kb[(size_t)(mbase + row) * 256 + c16 * 8] =
        *(const u16x8*)&Tw[row * 264 + c16 * 8];
  }
  // V transposed, kt-tiled: Vtt[(b*32+ktq)*8192 + d*32 + t_local]
#pragma unroll 4
  for (int nt2 = 0; nt2 < 16; ++nt2) {
    s16x8 aw = *(const s16x8*)&WqT[(size_t)(512 + nt2 * 16 + lo) * 32 + quad * 8];
    f32x4 c0 = {0.f, 0.f, 0.f, 0.f}, c1 = {0.f, 0.f, 0.f, 0.f};
    c0 = __builtin_amdgcn_mfma_f32_16x16x32_bf16(aw, af0, c0, 0, 0, 0);
    c1 = __builtin_amdgcn_mfma_f32_16x16x32_bf16(aw, af1, c1, 0, 0, 0);
#pragma unroll
    for (int i = 0; i < 4; ++i) {
      const int d = nt2 * 16 + quad * 4 + i;
      const float bv = Wcb[512 + d];
      Tw[d * 32 + lo]      = f2bf(c0[i] + bv);
      Tw[d * 32 + 16 + lo] = f2bf(c1[i] + bv);
    }
  }
  {
    const int ktq = (mbase >> 5) & 31;
    const size_t vb = ((size_t)b * 32 + ktq) * 8192;
#pragma unroll
    for (int it = 0; it < 16; ++it) {
      const int gsub = it * 64 + lane;
      *(u16x8*)&Vtt[vb + gsub * 8] = *(const u16x8*)&Tw[gsub * 8];
    }
  }
}

// ---------------- flash attention: barrier-free main loop, K/V from L2 ----------------
// 512 blocks x 256 thr. Block = (batch b XCD-pinned, pair p): tile p then tile 31-p
// (32 q-rows each) -> ~9 steps for EVERY block (uniform duration, all 2048 waves
// resident: 2 blocks/CU, 2 waves/SIMD). Within a tile the 4 waves split kt mod 4;
// partials are additive (fixed SM_M shift) and combined via LDS f32 tree.
// Swapped QK^T (S^T = mfma(K,Q)): lane owns q-column -> Ol is a per-lane scalar and
// P->A-fragment assembly is in-register (bf16 pack + 4 shfl_xor(32)). No K/V/P LDS.
__global__ __launch_bounds__(256, 2) void attn_kernel(const unsigned short* __restrict__ Qb,
                                                      const unsigned short* __restrict__ Kb,
                                                      const unsigned short* __restrict__ Vtt,
                                                      const unsigned short* __restrict__ WfT,
                                                      const float* __restrict__ bfp,
                                                      const float* __restrict__ x,
                                                      const float* __restrict__ sgpart,
                                                      float* __restrict__ lsum,
                                                      unsigned int* __restrict__ total,
                                                      float* __restrict__ out) {
  __shared__ float CO0[8192];   // 32 rows x 256 d fp32 combine buffer
  __shared__ float CO1[8192];
  __shared__ float OlL[4][32];
  __shared__ unsigned int flagv;
  const int g = blockIdx.x;
  const int b = (g & 7) * 4 + ((g >> 3) & 3);  // XCD (g%8) pinned: 4 batches per XCD
  const int p = g >> 5;                        // 0..15 -> tiles p and 31-p
  const int tid = threadIdx.x;
  const int w = tid >> 6, lane = tid & 63;
  const int cl = lane & 31, hi = lane >> 5;

  const unsigned short* KbB = Kb + (size_t)b * 262144;
  const unsigned short* VtB = Vtt + (size_t)b * 262144;

  float S_ = 0.f, SS = 0.f;
#pragma unroll
  for (int i = 0; i < 8; ++i) {
    S_ += sgpart[(b * 8 + i) * 2];
    SS += sgpart[(b * 8 + i) * 2 + 1];
  }
  const float mean = S_ * (1.f / (float)L_SZ);
  const float var = (SS - S_ * mean) * (1.f / (float)(L_SZ - 1));
  const float invb = 1.f / (sqrtf(var) + 1e-5f);
  float lacc = 0.f;

#pragma unroll 1
  for (int half = 0; half < 2; ++half) {
    const int ti = half ? (31 - p) : p;
    const int qr0 = ti * 32;

    // Q fragments (B-operand of swapped QK, A-operand role for PV rows): lane cl = q
    s16x8 qf[16];
    {
      const size_t qrow = ((size_t)b * 1024 + qr0 + cl) * 256;
#pragma unroll
      for (int cb = 0; cb < 16; ++cb)
        qf[cb] = *(const s16x8*)&Qb[qrow + cb * 16 + hi * 8];
    }

    f32x16 O[8];
#pragma unroll
    for (int dt = 0; dt < 8; ++dt)
#pragma unroll
      for (int i = 0; i < 16; ++i) O[dt][i] = 0.f;
    float Ol = 0.f;

    for (int kt = w; kt <= ti; kt += 4) {
      // S^T[32t x 32q] = K_tile . Q^T  (A = K: lane cl = key row; B = Q: lane cl = q)
      const unsigned short* kp = KbB + (size_t)kt * 8192 + cl * 256 + hi * 8;
      f32x16 Sx;
#pragma unroll
      for (int i = 0; i < 16; ++i) Sx[i] = 0.f;
#pragma unroll
      for (int cb = 0; cb < 16; ++cb) {
        s16x8 kf = *(const s16x8*)&kp[cb * 16];
        Sx = __builtin_amdgcn_mfma_f32_32x32x16_bf16(kf, qf[cb], Sx, 0, 0, 0);
      }
      // softmax numerator; C layout: col=q=cl, row=t=(r&3)+8(r>>2)+4hi
      float e[16];
      const bool diag = (kt == ti);
#pragma unroll
      for (int r = 0; r < 16; ++r) {
        const int trow = (r & 3) + 8 * (r >> 2) + 4 * hi;
        float ev = __expf(Sx[r] - SM_M);
        if (diag && trow > cl) ev = 0.f;
        e[r] = ev;
        Ol += ev;
      }
      // pack P^T column (this lane's q) into A-fragment words; exchange hi-halves
      u32 w8[8];
#pragma unroll
      for (int m = 0; m < 8; ++m)
        w8[m] = (u32)f2bf(e[2 * m]) | ((u32)f2bf(e[2 * m + 1]) << 16);
      const u32 r1 = (u32)__shfl_xor((int)(hi ? w8[0] : w8[2]), 32);
      const u32 r2 = (u32)__shfl_xor((int)(hi ? w8[1] : w8[3]), 32);
      const u32 r3 = (u32)__shfl_xor((int)(hi ? w8[4] : w8[6]), 32);
      const u32 r4 = (u32)__shfl_xor((int)(hi ? w8[5] : w8[7]), 32);
      union { u32x4 u; s16x8 s; } p0, p1;
      p0.u[0] = hi ? r1 : w8[0];
      p0.u[1] = hi ? r2 : w8[1];
      p0.u[2] = hi ? w8[2] : r1;
      p0.u[3] = hi ? w8[3] : r2;
      p1.u[0] = hi ? r3 : w8[4];
      p1.u[1] = hi ? r4 : w8[5];
      p1.u[2] = hi ? w8[6] : r3;
      p1.u[3] = hi ? w8[7] : r4;
      // PV: B = V^T tile (lane cl = d_local), accumulate O[q x d]
      const unsigned short* vp = VtB + (size_t)kt * 8192 + cl * 32 + hi * 8;
#pragma unroll
      for (int dt = 0; dt < 8; ++dt) {
        s16x8 v0 = *(const s16x8*)&vp[dt * 1024];
        s16x8 v1 = *(const s16x8*)&vp[dt * 1024 + 16];
        O[dt] = __builtin_amdgcn_mfma_f32_32x32x16_bf16(p0.s, v0, O[dt], 0, 0, 0);
        O[dt] = __builtin_amdgcn_mfma_f32_32x32x16_bf16(p1.s, v1, O[dt], 0, 0, 0);
      }
    }
    Ol += __shfl_xor(Ol, 32);  // both hi-halves of column q

    // ---- combine partial O across the 4 kt-parity waves (fixed tree order) ----
    __syncthreads();  // protects CO reuse vs previous half's epilogue
    if (w == 1) {
#pragma unroll
      for (int dt = 0; dt < 8; ++dt)
#pragma unroll
        for (int r = 0; r < 16; ++r) {
          const int row = (r & 3) + 8 * (r >> 2) + 4 * hi;
          CO0[row * 256 + dt * 32 + cl] = O[dt][r];
        }
    }
    if (w == 3) {
#pragma unroll
      for (int dt = 0; dt < 8; ++dt)
#pragma unroll
        for (int r = 0; r < 16; ++r) {
          const int row = (r & 3) + 8 * (r >> 2) + 4 * hi;
          CO1[row * 256 + dt * 32 + cl] = O[dt][r];
        }
    }
    if (hi == 0) OlL[w][cl] = Ol;
    __syncthreads();
    if (w == 0) {
#pragma unroll
      for (int dt = 0; dt < 8; ++dt)
#pragma unroll
        for (int r = 0; r < 16; ++r) {
          const int row = (r & 3) + 8 * (r >> 2) + 4 * hi;
          O[dt][r] += CO0[row * 256 + dt * 32 + cl];
        }
    }
    if (w == 2) {
#pragma unroll
      for (int dt = 0; dt < 8; ++dt)
#pragma unroll
        for (int r = 0; r < 16; ++r) {
          const int row = (r & 3) + 8 * (r >> 2) + 4 * hi;
          O[dt][r] += CO1[row * 256 + dt * 32 + cl];
        }
    }
    __syncthreads();
    if (w == 2) {
#pragma unroll
      for (int dt = 0; dt < 8; ++dt)
#pragma unroll
        for (int r = 0; r < 16; ++r) {
          const int row = (r & 3) + 8 * (r >> 2) + 4 * hi;
          CO0[row * 256 + dt * 32 + cl] = O[dt][r];
        }
    }
    __syncthreads();
    if (w == 0) {
#pragma unroll
      for (int dt = 0; dt < 8; ++dt)
#pragma unroll
        for (int r = 0; r < 16; ++r) {
          const int row = (r & 3) + 8 * (r >> 2) + 4 * hi;
          O[dt][r] += CO0[row * 256 + dt * 32 + cl];
        }
      // ---- epilogue (wave 0): normalize -> OLw A-layout -> head GEMM -> MSE ----
      float ivr[16];
#pragma unroll
      for (int r = 0; r < 16; ++r) {
        const int row = (r & 3) + 8 * (r >> 2) + 4 * hi;
        ivr[r] = 1.f / (OlL[0][row] + OlL[1][row] + OlL[2][row] + OlL[3][row]);
      }
      unsigned short* OLw = (unsigned short*)CO0;  // overlay (wave0-exclusive now)
#pragma unroll
      for (int dt = 0; dt < 8; ++dt)
#pragma unroll
        for (int r = 0; r < 16; ++r) {
          const int row = (r & 3) + 8 * (r >> 2) + 4 * hi;
          OLw[row * 264 + dt * 32 + cl] = f2bf(O[dt][r] * ivr[r]);
        }
      s16x8 af[16];
#pragma unroll
      for (int cb = 0; cb < 16; ++cb)
        af[cb] = *(const s16x8*)&OLw[cl * 264 + cb * 16 + hi * 8];
      f32x16 hacc;
#pragma unroll
      for (int i = 0; i < 16; ++i) hacc[i] = 0.f;
#pragma unroll
      for (int cb = 0; cb < 16; ++cb) {
        s16x8 bfr = *(const s16x8*)&WfT[(size_t)cl * 256 + cb * 16 + hi * 8];
        hacc = __builtin_amdgcn_mfma_f32_32x32x16_bf16(af[cb], bfr, hacc, 0, 0, 0);
      }
      const float ba = bfp[cl];
#pragma unroll
      for (int r = 0; r < 16; ++r) {
        const int row = (r & 3) + 8 * (r >> 2) + 4 * hi;
        const int t = qr0 + row;
        if (t < 1023) {
          const float pr = hacc[r] + ba;
          const float tg = (x[(size_t)b * L_SZ + (t + 1) * 32 + cl] - mean) * invb;
          const float d = pr - tg;
          lacc += d * d;
        }
      }
    }
  }

  // ---- loss: only wave 0 holds contributions; reduce and finalize ----
#pragma unroll
  for (int off = 32; off >= 1; off >>= 1) lacc += __shfl_down(lacc, off);
  if (tid == 0) {
    atomicAdd(lsum, lacc);
    __threadfence();
    unsigned int prev = atomicAdd(total, 1u);
    flagv = (prev == 511u) ? 1u : 0u;
  }
  __syncthreads();
  if (flagv && tid == 0) {
    float tot = atomicAdd(lsum, 0.0f);  // device-scope read including all adds
    out[0] = tot * (1.f / (float)(B_SZ * (T_SZ - 1) * PS_SZ));
  }
}

extern "C" void kernel_launch(void* const* d_in, const int* in_sizes, int n_in,
                              void* d_out, int out_size, void* d_ws, size_t ws_size,
                              hipStream_t stream) {
  const float* x      = (const float*)d_in[0];
  const float* W_proj = (const float*)d_in[1];
  const float* b_proj = (const float*)d_in[2];
  const float* W_qkv  = (const float*)d_in[3];
  const float* b_qkv  = (const float*)d_in[4];
  const float* W_out  = (const float*)d_in[5];
  const float* b_out  = (const float*)d_in[6];
  const float* W_head = (const float*)d_in[7];
  const float* b_head = (const float*)d_in[8];
  float* out = (float*)d_out;
  char* ws = (char*)d_ws;

  unsigned short* Qb     = (unsigned short*)ws;
  unsigned short* Kb     = (unsigned short*)(ws + (16ull << 20));
  unsigned short* Vtt    = (unsigned short*)(ws + (32ull << 20));
  char* tail = ws + (48ull << 20);
  float*          Wcb    = (float*)tail;                        // 768 fp32 folded qkv bias
  unsigned short* WqT    = (unsigned short*)(tail + 4096);      // 768x32 bf16
  unsigned short* WfT    = (unsigned short*)(tail + 65536);     // 32x256 bf16
  float*          bfp    = (float*)(tail + 98304);              // 32 fp32
  float*          sgpart = (float*)(tail + 102400);             // 256x2 fp32
  unsigned int*   total  = (unsigned int*)(tail + 106496);      // 1 ctr
  float*          lsum   = (float*)(tail + 106496 + 64);        // 1 fp32

  prep_kernel<<<389, 256, 0, stream>>>(x, sgpart, W_proj, b_proj, W_qkv, b_qkv,
                                       W_out, b_out, W_head, b_head,
                                       Wcb, WqT, WfT, bfp, total, lsum);
  qkv_kernel<<<256, 256, 0, stream>>>(x, sgpart, WqT, Wcb, Qb, Kb, Vtt);
  attn_kernel<<<512, 256, 0, stream>>>(Qb, Kb, Vtt, WfT, bfp, x, sgpart, lsum, total, out);
}